// Round 17
// baseline (503.527 us; speedup 1.0000x reference)
//
#include <hip/hip_runtime.h>
#include <hip/hip_bf16.h>
#include <math.h>

#define V 32000
#define B 32
#define E 64
#define H 256
#define T 128
#define NROW (B*T)     // 4096 rows, row = t*B + b
#define NC2 64         // vocab cols per logits block
#define NVB2 (V/NC2)   // 500

typedef __attribute__((ext_vector_type(8))) short bf16x8;
typedef __attribute__((ext_vector_type(4))) float f32x4;
typedef __attribute__((ext_vector_type(8))) unsigned short u16x8;

// ws layout (float offsets)
#define OFF_XS   0                          // xs fp32 [T*B][E]              1MB
#define OFF_XW   (OFF_XS + NROW*E)          // xwq bf16 8MB; WoT bf16 16MB aliases after recur
#define OFF_HB   (OFF_XW + NROW*4*H)        // hb bf16 [t*B+b][k]            2MB
#define OFF_PS   (OFF_HB + NROW*H/2)        // ps fp32 [NVB2][NROW]          8MB
#define OFF_TL   (OFF_PS + NVB2*NROW)       // tl fp32 [NROW]
#define OFF_U8   (OFF_TL + NROW)            // UQ8 i8 [k4][j][g*4+kk]        256KB
#define OFF_SC   (OFF_U8 + H*H)             // per-gate scales, 4 floats
#define OFF_TGT  (OFF_SC + 16)              // tgtrow int [NROW]             16KB

static __device__ __forceinline__ unsigned short f2bf(float f) {
    union { float f; unsigned int u; } x; x.f = f;
    unsigned int r = x.u + 0x7fffu + ((x.u >> 16) & 1u);   // RNE
    return (unsigned short)(r >> 16);
}
static __device__ __forceinline__ float bf2f(unsigned short u) {
    union { unsigned int u; float f; } x; x.u = ((unsigned int)u) << 16; return x.f;
}
static __device__ __forceinline__ float sigmoidf_(float x) { return 1.f / (1.f + __expf(-x)); }
static __device__ __forceinline__ float tanhf_(float x)    { return 2.f / (1.f + __expf(-2.f * x)) - 1.f; }

#if defined(__has_builtin)
#if __has_builtin(__builtin_amdgcn_sdot4)
#define HAVE_SDOT4 1
#endif
#if __has_builtin(__builtin_amdgcn_global_load_lds)
#define HAVE_GLL 1
#endif
#endif
static __device__ __forceinline__ int dot4i8(unsigned int a, unsigned int b, int c) {
#ifdef HAVE_SDOT4
    return __builtin_amdgcn_sdot4((int)a, (int)b, c, false);
#else
    c += (int)(char)(a)       * (int)(char)(b);
    c += (int)(char)(a >> 8)  * (int)(char)(b >> 8);
    c += (int)(char)(a >> 16) * (int)(char)(b >> 16);
    c += (int)(char)(a >> 24) * (int)(char)(b >> 24);
    return c;
#endif
}
// async 16B global->LDS; builtin path: g per-lane, l wave-uniform (HW adds lane*16)
static __device__ __forceinline__ void stage16(const char* g, char* l, int lane) {
#ifdef HAVE_GLL
    __builtin_amdgcn_global_load_lds(
        (const __attribute__((address_space(1))) void*)g,
        (__attribute__((address_space(3))) void*)l, 16, 0, 0);
    (void)lane;
#else
    *(uint4*)(l + lane * 16) = *(const uint4*)g;
#endif
}

// ---- D1: embedding gather + tgtrow + out zero  ||  per-gate absmax of U -----
__global__ __launch_bounds__(256) void lstm_embed_umax(
        const int* __restrict__ x, const float* __restrict__ emb,
        const int* __restrict__ start, float* __restrict__ xs,
        float* __restrict__ out, int* __restrict__ tgtrow,
        const float* __restrict__ Ui, const float* __restrict__ Uf,
        const float* __restrict__ Uog, const float* __restrict__ Uc,
        float* __restrict__ sc) {
    __shared__ float red[256];
    const int tid = threadIdx.x;
    if (blockIdx.x >= 1024) {                 // ---- umax path (4 blocks) ----
        const int g = blockIdx.x - 1024;
        const float* U = (g == 0) ? Ui : (g == 1) ? Uf : (g == 2) ? Uog : Uc;
        float m = 0.f;
        for (int i = tid; i < H * H; i += 256) m = fmaxf(m, fabsf(U[i]));
        red[tid] = m;
        __syncthreads();
        for (int off = 128; off > 0; off >>= 1) {
            if (tid < off) red[tid] = fmaxf(red[tid], red[tid + off]);
            __syncthreads();
        }
        if (tid == 0) sc[g] = fmaxf(red[0], 1e-20f);
        return;
    }
    int idx = blockIdx.x * 256 + tid;         // ---- embed path (1024 blocks, exact) ----
    if (idx == 0) out[0] = 0.f;               // zero accumulator each launch (graph-replay safe)
    if (idx < NROW) tgtrow[idx] = x[(idx & 31) * T + (idx >> 5)];   // tgt of row gr=t*32+b
    int t   = idx / (B * E);
    int rem = idx - t * (B * E);
    int b   = rem >> 6;
    int e   = rem & 63;
    int tok = (t == 0) ? start[0] : x[b * T + (t - 1)];
    xs[idx] = emb[tok * E + e];
}

// ---- D2: xw (128 blocks)  ||  uq8 (64 blocks)  ||  wot (2000 blocks) --------
__global__ __launch_bounds__(256) void lstm_xw_uq8_wot(
        const float* __restrict__ xs, unsigned short* __restrict__ xwq,
        const float* __restrict__ Wi, const float* __restrict__ Wf,
        const float* __restrict__ Wog, const float* __restrict__ Wc,
        const float* __restrict__ bi, const float* __restrict__ bf,
        const float* __restrict__ bog, const float* __restrict__ bc,
        const float* __restrict__ Ui, const float* __restrict__ Uf,
        const float* __restrict__ Uog, const float* __restrict__ Uc,
        const float* __restrict__ sc, unsigned int* __restrict__ UQ8,
        const float* __restrict__ Wo, unsigned short* __restrict__ WoT) {
    __shared__ union {
        float xsl[32][65];
        unsigned short tle[64][65];
    } smu;
    const int blk = blockIdx.x, tid = threadIdx.x;
    if (blk < T) {
        // ---- xw: xwq[t*32+b][j][g] bf16 = xs @ W_g + bias_g ----
        const int t = blk;
        for (int i = tid; i < 32 * 64; i += 256) {
            int b = i >> 6, e = i & 63;
            smu.xsl[b][e] = xs[(size_t)(t * 32 + b) * 64 + e];
        }
        __syncthreads();
        const int b = tid & 31, jg = tid >> 5;
        for (int jj = 0; jj < 32; ++jj) {
            const int j = jg * 32 + jj;
            float a0 = bi[j], a1 = bf[j], a2 = bog[j], a3 = bc[j];
            #pragma unroll 8
            for (int e = 0; e < E; ++e) {
                float xe = smu.xsl[b][e];
                a0 += xe * Wi [e * H + j];
                a1 += xe * Wf [e * H + j];
                a2 += xe * Wog[e * H + j];
                a3 += xe * Wc [e * H + j];
            }
            ushort4 v;
            v.x = f2bf(a0); v.y = f2bf(a1); v.z = f2bf(a2); v.w = f2bf(a3);
            *(ushort4*)(xwq + ((size_t)(t * 32 + b) * 256 + j) * 4) = v;
        }
    } else if (blk < T + 64) {
        // ---- uq8: U_g fp32 -> UQ8[k4][j] 16B ----
        const int idx = (blk - T) * 256 + tid;
        const int k4 = idx >> 8, j = idx & 255;
        float inv[4] = { 127.f / sc[0], 127.f / sc[1], 127.f / sc[2], 127.f / sc[3] };
        const float* Ug[4] = { Ui, Uf, Uog, Uc };
        uint4 outw;
        unsigned int* op = (unsigned int*)&outw;
        #pragma unroll
        for (int g = 0; g < 4; ++g) {
            unsigned int w = 0;
            #pragma unroll
            for (int kk = 0; kk < 4; ++kk) {
                float v = Ug[g][(size_t)(k4 * 4 + kk) * H + j];
                int q = __float2int_rn(v * inv[g]);
                q = q > 127 ? 127 : (q < -127 ? -127 : q);
                w |= ((unsigned int)(q & 255)) << (kk * 8);
            }
            op[g] = w;
        }
        *(uint4*)(UQ8 + (size_t)idx * 4) = outw;
    } else {
        // ---- wot: Wo [K=256][V] fp32 -> WoT [V][K=256] bf16 ----
        const int w2 = blk - T - 64;
        const int n0 = (w2 % 500) * 64, k0 = (w2 / 500) * 64;
        for (int i = tid; i < 64 * 64; i += 256) {
            int kk = i >> 6, nn = i & 63;
            smu.tle[kk][nn] = f2bf(Wo[(size_t)(k0 + kk) * V + n0 + nn]);
        }
        __syncthreads();
        for (int c = tid; c < 512; c += 256) {
            int nn = c >> 3, kc = c & 7;
            u16x8 v;
            #pragma unroll
            for (int e = 0; e < 8; ++e) v[e] = smu.tle[kc * 8 + e][nn];
            *(u16x8*)(WoT + (size_t)(n0 + nn) * H + k0 + kc * 8) = v;
        }
    }
}

// ---- D3: recurrence — 32 independent blocks (1/batch row), i8 dot4 ----------
__global__ __launch_bounds__(1024) void lstm_recur_i8(
        const unsigned short* __restrict__ xwq, const uint4* __restrict__ UQ8,
        const float* __restrict__ sc, unsigned short* __restrict__ hb) {
    __shared__ unsigned int hq8[2][64];     // int8 h, ping-pong, 4 k per dword
    __shared__ int4 red[4][256];            // per-quarter gate sums
    const int b = blockIdx.x, tid = threadIdx.x;
    const int j = tid & 255, q = tid >> 8;
    const float f0 = sc[0] * (1.f / 16129.f), f1 = sc[1] * (1.f / 16129.f);
    const float f2 = sc[2] * (1.f / 16129.f), f3 = sc[3] * (1.f / 16129.f);
    float c_ = 0.f;

    for (int t = 0; t < T; ++t) {
        if (t > 0) {
            const uint4* up = UQ8 + (size_t)(q * 16) * 256 + j;
            const unsigned int* hrow = hq8[t & 1] + q * 16;
            int a0 = 0, a1 = 0, a2 = 0, a3 = 0;
            #pragma unroll
            for (int m = 0; m < 16; ++m) {
                uint4 u = up[(size_t)m * 256];
                unsigned int hv = hrow[m];
                a0 = dot4i8(u.x, hv, a0);
                a1 = dot4i8(u.y, hv, a1);
                a2 = dot4i8(u.z, hv, a2);
                a3 = dot4i8(u.w, hv, a3);
            }
            red[q][j] = make_int4(a0, a1, a2, a3);
        }
        __syncthreads();
        if (tid < 256) {
            ushort4 xw = *(const ushort4*)(xwq + ((size_t)(t * 32 + b) * 256 + j) * 4);
            float pi = bf2f(xw.x), pf = bf2f(xw.y), po = bf2f(xw.z), pc = bf2f(xw.w);
            if (t > 0) {
                int4 r0 = red[0][j], r1 = red[1][j], r2 = red[2][j], r3 = red[3][j];
                pi += (float)(r0.x + r1.x + r2.x + r3.x) * f0;
                pf += (float)(r0.y + r1.y + r2.y + r3.y) * f1;
                po += (float)(r0.z + r1.z + r2.z + r3.z) * f2;
                pc += (float)(r0.w + r1.w + r2.w + r3.w) * f3;
            }
            c_ = sigmoidf_(pf) * c_ + sigmoidf_(pi) * tanhf_(pc);
            float h = sigmoidf_(po) * tanhf_(c_);
            hb[(size_t)(t * B + b) * H + j] = f2bf(h);
            ((char*)hq8[(t + 1) & 1])[j] = (char)__float2int_rn(h * 127.f);
        }
        __syncthreads();
    }
}

// ---- D4: logits GEMM — NC2=64 cols/block so Bf = 32 VGPR: total live ~55
// arch-VGPRs stays UNDER the 64-reg HW granularity cliff (m69: waves/CU
// halves above 64) -> 2 blocks/CU co-resident AND no spill (r15 had the
// occupancy but spilled; r16 had no spill but 1 block/CU).
// grid (500 vchunks, 2 row-halves); dbuf A (32KB tiles) with prefetch-ahead
// global_load_lds; max-free fused softmax; tgt_l race fixed (write for rb+1
// sits between the two trailing barriers).
__global__ __launch_bounds__(512, 4) void lstm_logits_mfma(
        const unsigned short* __restrict__ hb, const unsigned short* __restrict__ WoT,
        const float* __restrict__ bo, const int* __restrict__ tgtrow,
        float* __restrict__ ps, float* __restrict__ tl) {
    __shared__ char ab0[32768];          // 64-row tile buffer 0
    __shared__ char ab1[32768];          // 64-row tile buffer 1
    __shared__ float s_red[4][72];       // per-colwave row sums (pad)
    __shared__ int   tgt_l[64];
    const int tid = threadIdx.x, lane = tid & 63, wid = tid >> 6;   // 8 waves
    const int wr = wid >> 2, wc = wid & 3;          // 2 row-32s x 4 col-16s
    const int lr = lane & 15, lg = lane >> 4;
    const int swz = lr & 7;
    const int vb = blockIdx.x * NC2;
    const int rbase = blockIdx.y * (NROW / 2);      // this block's 2048 rows

    // stage one 32KB 64-row tile: 8 waves x 4 instr x (64 lanes x 16B)
    // linear LDS dest + pre-swizzled source + swizzled read (verified r13-r16)
    #define STAGE32(dst_, srcbase_) { _Pragma("unroll") \
        for (int i_ = 0; i_ < 4; ++i_) { \
            int chunk_ = (wid * 4 + i_) * 64 + lane; \
            int row_ = chunk_ >> 5, c16_ = chunk_ & 31; \
            int srcc_ = c16_ ^ (row_ & 7); \
            stage16((const char*)(srcbase_) + row_ * 512 + srcc_ * 16, \
                    (dst_) + (wid * 4 + i_) * 1024, lane); \
        } }

    // ---- prologue: B slice (64 rows) -> ab0 -> 32 VGPR ----
    STAGE32(ab0, (const char*)(WoT + (size_t)vb * H));
    if (tid < 64) tgt_l[tid] = tgtrow[rbase + tid];   // targets for rb=0
    __syncthreads();                                  // drains vmcnt+lgkmcnt
    bf16x8 Bf[8];
    {
        const char* bBase = ab0 + (wc * 16 + lr) * 512;
        #pragma unroll
        for (int ks = 0; ks < 8; ++ks)
            Bf[ks] = *(const bf16x8*)(bBase + (((ks * 4 + lg) ^ swz) << 4));
    }
    const float bocol = bo[vb + wc * 16 + lr];
    __syncthreads();                                  // Bf reads drained everywhere
    STAGE32(ab0, (const char*)(hb + (size_t)rbase * H));            // A tile 0
    __syncthreads();                                  // A0 landed

    for (int rb = 0; rb < 32; ++rb) {                 // 32 x 64-row tiles
        char* curb = (rb & 1) ? ab1 : ab0;
        char* nxtb = (rb & 1) ? ab0 : ab1;
        if (rb + 1 < 32)                              // prefetch A[rb+1] (async)
            STAGE32(nxtb, (const char*)(hb + (size_t)(rbase + (rb + 1) * 64) * H));

        f32x4 acc[2] = {};
        const char* aBase = curb + (wr * 32 + lr) * 512;
        #pragma unroll
        for (int ks = 0; ks < 8; ++ks) {
            const int co = ((ks * 4 + lg) ^ swz) << 4;
            bf16x8 a0 = *(const bf16x8*)(aBase + co);
            bf16x8 a1 = *(const bf16x8*)(aBase + 16 * 512 + co);
            acc[0] = __builtin_amdgcn_mfma_f32_16x16x32_bf16(a0, Bf[ks], acc[0], 0, 0, 0);
            acc[1] = __builtin_amdgcn_mfma_f32_16x16x32_bf16(a1, Bf[ks], acc[1], 0, 0, 0);
        }

        // ---- fused softmax partials, in-register ----
        const int col0 = vb + wc * 16 + lr;
        #pragma unroll
        for (int mf = 0; mf < 2; ++mf)
            #pragma unroll
            for (int r = 0; r < 4; ++r) {
                const int row_l = wr * 32 + mf * 16 + lg * 4 + r;
                float v0 = acc[mf][r] + bocol;
                if (tgt_l[row_l] == col0) tl[rbase + rb * 64 + row_l] = v0;
                float e = __expf(v0);
                e += __shfl_xor(e, 1); e += __shfl_xor(e, 2);
                e += __shfl_xor(e, 4); e += __shfl_xor(e, 8);
                if (lr == 0) s_red[wc][row_l] = e;
            }
        __syncthreads();                              // s_red ready (also drains prefetch)
        if (tid < 64) {
            ps[(size_t)blockIdx.x * NROW + rbase + rb * 64 + tid] =
                s_red[0][tid] + s_red[1][tid] + s_red[2][tid] + s_red[3][tid];
            if (rb + 1 < 32)                          // targets for rb+1 (published by barrier below)
                tgt_l[tid] = tgtrow[rbase + (rb + 1) * 64 + tid];
        }
        __syncthreads();                              // s_red consumed + tgt_l/A[rb+1] published
    }
    #undef STAGE32
}

// ---- D5: combine chunk sums, reduce NLL — 64 blocks, 4 c-quarters/row --------
__global__ __launch_bounds__(256) void lstm_lse(
        const float* __restrict__ ps, const float* __restrict__ tl,
        float* __restrict__ out) {
    __shared__ float sp[4][80];
    const int tid = threadIdx.x;
    const int rl = tid & 63, cq = tid >> 6;
    const int row = blockIdx.x * 64 + rl;
    float s = 0.f;
    #pragma unroll 4
    for (int c = cq; c < NVB2; c += 4)
        s += ps[(size_t)c * NROW + row];
    sp[cq][rl] = s;
    __syncthreads();
    if (tid < 64) {
        float nll = logf(sp[0][rl] + sp[1][rl] + sp[2][rl] + sp[3][rl]) - tl[row];
        #pragma unroll
        for (int off = 32; off > 0; off >>= 1) nll += __shfl_xor(nll, off);
        if (rl == 0) atomicAdd(out, nll);
    }
}

extern "C" void kernel_launch(void* const* d_in, const int* in_sizes, int n_in,
                              void* d_out, int out_size, void* d_ws, size_t ws_size,
                              hipStream_t stream) {
    const int*   x     = (const int*)d_in[0];
    const float* emb   = (const float*)d_in[1];
    const float* Wi    = (const float*)d_in[2];
    const float* Ui    = (const float*)d_in[3];
    const float* bi    = (const float*)d_in[4];
    const float* Wf    = (const float*)d_in[5];
    const float* Uf    = (const float*)d_in[6];
    const float* bf    = (const float*)d_in[7];
    const float* Wog   = (const float*)d_in[8];
    const float* Uog   = (const float*)d_in[9];
    const float* bog   = (const float*)d_in[10];
    const float* Wc    = (const float*)d_in[11];
    const float* Uc    = (const float*)d_in[12];
    const float* bc    = (const float*)d_in[13];
    const float* Wo    = (const float*)d_in[14];
    const float* bo    = (const float*)d_in[15];
    const int*   start = (const int*)d_in[16];
    float* ws  = (float*)d_ws;
    float* out = (float*)d_out;

    float*          xs   = ws + OFF_XS;
    unsigned short* xwq  = (unsigned short*)(ws + OFF_XW);
    unsigned short* WoT  = (unsigned short*)(ws + OFF_XW);   // aliases xwq (dead after recur)
    unsigned short* hbf  = (unsigned short*)(ws + OFF_HB);
    float*          psB  = ws + OFF_PS;
    float*          tlB  = ws + OFF_TL;
    unsigned int*   UQ8  = (unsigned int*)(ws + OFF_U8);
    float*          scB  = ws + OFF_SC;
    int*            tgtr = (int*)(ws + OFF_TGT);

    // D1: embed (1024 blocks) || umax (4 blocks)
    lstm_embed_umax<<<1028, 256, 0, stream>>>(x, emb, start, xs, out, tgtr,
                                              Ui, Uf, Uog, Uc, scB);
    // D2: xw (128) || uq8 (64) || wot (2000)
    lstm_xw_uq8_wot<<<T + 64 + 2000, 256, 0, stream>>>(
        xs, xwq, Wi, Wf, Wog, Wc, bi, bf, bog, bc,
        Ui, Uf, Uog, Uc, scB, UQ8, Wo, WoT);
    // D3: recurrence
    lstm_recur_i8<<<B, 1024, 0, stream>>>(xwq, (const uint4*)UQ8, scB, hbf);
    // D4: logits + fused softmax partials
    lstm_logits_mfma<<<dim3(NVB2, 2), 512, 0, stream>>>(hbf, WoT, bo, tgtr, psB, tlB);
    // D5: combine + NLL
    lstm_lse<<<NROW / 64, 256, 0, stream>>>(psB, tlB, out);
}

// Round 18
// 442.767 us; speedup vs baseline: 1.1372x; 1.1372x over previous
//
#include <hip/hip_runtime.h>
#include <hip/hip_bf16.h>
#include <math.h>

#define V 32000
#define B 32
#define E 64
#define H 256
#define T 128
#define NROW (B*T)     // 4096 rows, row = t*B + b
#define NC 128         // vocab cols per logits block
#define NVB (V/NC)     // 250

typedef __attribute__((ext_vector_type(8))) short bf16x8;
typedef __attribute__((ext_vector_type(4))) float f32x4;
typedef __attribute__((ext_vector_type(8))) unsigned short u16x8;

// ws layout (float offsets)
#define OFF_XS   0                          // xs fp32 [T*B][E]              1MB
#define OFF_XW   (OFF_XS + NROW*E)          // xwq bf16 8MB; WoT bf16 16MB aliases after recur
#define OFF_HB   (OFF_XW + NROW*4*H)        // hb bf16 [t*B+b][k]            2MB
#define OFF_PS   (OFF_HB + NROW*H/2)        // ps fp32 [NVB][NROW]           4MB
#define OFF_TL   (OFF_PS + NVB*NROW)        // tl fp32 [NROW]
#define OFF_U8   (OFF_TL + NROW)            // UQ8 i8 [k4][j][g*4+kk]        256KB
#define OFF_SC   (OFF_U8 + H*H)             // per-gate scales, 4 floats
#define OFF_TGT  (OFF_SC + 16)              // tgtrow int [NROW]             16KB

static __device__ __forceinline__ unsigned short f2bf(float f) {
    union { float f; unsigned int u; } x; x.f = f;
    unsigned int r = x.u + 0x7fffu + ((x.u >> 16) & 1u);   // RNE
    return (unsigned short)(r >> 16);
}
static __device__ __forceinline__ float bf2f(unsigned short u) {
    union { unsigned int u; float f; } x; x.u = ((unsigned int)u) << 16; return x.f;
}
static __device__ __forceinline__ float sigmoidf_(float x) { return 1.f / (1.f + __expf(-x)); }
static __device__ __forceinline__ float tanhf_(float x)    { return 2.f / (1.f + __expf(-2.f * x)) - 1.f; }

#if defined(__has_builtin)
#if __has_builtin(__builtin_amdgcn_sdot4)
#define HAVE_SDOT4 1
#endif
#if __has_builtin(__builtin_amdgcn_global_load_lds)
#define HAVE_GLL 1
#endif
#endif
static __device__ __forceinline__ int dot4i8(unsigned int a, unsigned int b, int c) {
#ifdef HAVE_SDOT4
    return __builtin_amdgcn_sdot4((int)a, (int)b, c, false);
#else
    c += (int)(char)(a)       * (int)(char)(b);
    c += (int)(char)(a >> 8)  * (int)(char)(b >> 8);
    c += (int)(char)(a >> 16) * (int)(char)(b >> 16);
    c += (int)(char)(a >> 24) * (int)(char)(b >> 24);
    return c;
#endif
}
// async 16B global->LDS; builtin path: g per-lane, l wave-uniform (HW adds lane*16)
static __device__ __forceinline__ void stage16(const char* g, char* l, int lane) {
#ifdef HAVE_GLL
    __builtin_amdgcn_global_load_lds(
        (const __attribute__((address_space(1))) void*)g,
        (__attribute__((address_space(3))) void*)l, 16, 0, 0);
    (void)lane;
#else
    *(uint4*)(l + lane * 16) = *(const uint4*)g;
#endif
}

// ---- D1: embedding gather + tgtrow + out zero  ||  per-gate absmax of U -----
__global__ __launch_bounds__(256) void lstm_embed_umax(
        const int* __restrict__ x, const float* __restrict__ emb,
        const int* __restrict__ start, float* __restrict__ xs,
        float* __restrict__ out, int* __restrict__ tgtrow,
        const float* __restrict__ Ui, const float* __restrict__ Uf,
        const float* __restrict__ Uog, const float* __restrict__ Uc,
        float* __restrict__ sc) {
    __shared__ float red[256];
    const int tid = threadIdx.x;
    if (blockIdx.x >= 1024) {                 // ---- umax path (4 blocks) ----
        const int g = blockIdx.x - 1024;
        const float* U = (g == 0) ? Ui : (g == 1) ? Uf : (g == 2) ? Uog : Uc;
        float m = 0.f;
        for (int i = tid; i < H * H; i += 256) m = fmaxf(m, fabsf(U[i]));
        red[tid] = m;
        __syncthreads();
        for (int off = 128; off > 0; off >>= 1) {
            if (tid < off) red[tid] = fmaxf(red[tid], red[tid + off]);
            __syncthreads();
        }
        if (tid == 0) sc[g] = fmaxf(red[0], 1e-20f);
        return;
    }
    int idx = blockIdx.x * 256 + tid;         // ---- embed path (1024 blocks, exact) ----
    if (idx == 0) out[0] = 0.f;               // zero accumulator each launch (graph-replay safe)
    if (idx < NROW) tgtrow[idx] = x[(idx & 31) * T + (idx >> 5)];   // tgt of row gr=t*32+b
    int t   = idx / (B * E);
    int rem = idx - t * (B * E);
    int b   = rem >> 6;
    int e   = rem & 63;
    int tok = (t == 0) ? start[0] : x[b * T + (t - 1)];
    xs[idx] = emb[tok * E + e];
}

// ---- D2: xw (128 blocks)  ||  uq8 (64 blocks)  ||  wot (2000 blocks) --------
__global__ __launch_bounds__(256) void lstm_xw_uq8_wot(
        const float* __restrict__ xs, unsigned short* __restrict__ xwq,
        const float* __restrict__ Wi, const float* __restrict__ Wf,
        const float* __restrict__ Wog, const float* __restrict__ Wc,
        const float* __restrict__ bi, const float* __restrict__ bf,
        const float* __restrict__ bog, const float* __restrict__ bc,
        const float* __restrict__ Ui, const float* __restrict__ Uf,
        const float* __restrict__ Uog, const float* __restrict__ Uc,
        const float* __restrict__ sc, unsigned int* __restrict__ UQ8,
        const float* __restrict__ Wo, unsigned short* __restrict__ WoT) {
    __shared__ union {
        float xsl[32][65];
        unsigned short tle[64][65];
    } smu;
    const int blk = blockIdx.x, tid = threadIdx.x;
    if (blk < T) {
        // ---- xw: xwq[t*32+b][j][g] bf16 = xs @ W_g + bias_g ----
        const int t = blk;
        for (int i = tid; i < 32 * 64; i += 256) {
            int b = i >> 6, e = i & 63;
            smu.xsl[b][e] = xs[(size_t)(t * 32 + b) * 64 + e];
        }
        __syncthreads();
        const int b = tid & 31, jg = tid >> 5;
        for (int jj = 0; jj < 32; ++jj) {
            const int j = jg * 32 + jj;
            float a0 = bi[j], a1 = bf[j], a2 = bog[j], a3 = bc[j];
            #pragma unroll 8
            for (int e = 0; e < E; ++e) {
                float xe = smu.xsl[b][e];
                a0 += xe * Wi [e * H + j];
                a1 += xe * Wf [e * H + j];
                a2 += xe * Wog[e * H + j];
                a3 += xe * Wc [e * H + j];
            }
            ushort4 v;
            v.x = f2bf(a0); v.y = f2bf(a1); v.z = f2bf(a2); v.w = f2bf(a3);
            *(ushort4*)(xwq + ((size_t)(t * 32 + b) * 256 + j) * 4) = v;
        }
    } else if (blk < T + 64) {
        // ---- uq8: U_g fp32 -> UQ8[k4][j] 16B ----
        const int idx = (blk - T) * 256 + tid;
        const int k4 = idx >> 8, j = idx & 255;
        float inv[4] = { 127.f / sc[0], 127.f / sc[1], 127.f / sc[2], 127.f / sc[3] };
        const float* Ug[4] = { Ui, Uf, Uog, Uc };
        uint4 outw;
        unsigned int* op = (unsigned int*)&outw;
        #pragma unroll
        for (int g = 0; g < 4; ++g) {
            unsigned int w = 0;
            #pragma unroll
            for (int kk = 0; kk < 4; ++kk) {
                float v = Ug[g][(size_t)(k4 * 4 + kk) * H + j];
                int q = __float2int_rn(v * inv[g]);
                q = q > 127 ? 127 : (q < -127 ? -127 : q);
                w |= ((unsigned int)(q & 255)) << (kk * 8);
            }
            op[g] = w;
        }
        *(uint4*)(UQ8 + (size_t)idx * 4) = outw;
    } else {
        // ---- wot: Wo [K=256][V] fp32 -> WoT [V][K=256] bf16 ----
        const int w2 = blk - T - 64;
        const int n0 = (w2 % 500) * 64, k0 = (w2 / 500) * 64;
        for (int i = tid; i < 64 * 64; i += 256) {
            int kk = i >> 6, nn = i & 63;
            smu.tle[kk][nn] = f2bf(Wo[(size_t)(k0 + kk) * V + n0 + nn]);
        }
        __syncthreads();
        for (int c = tid; c < 512; c += 256) {
            int nn = c >> 3, kc = c & 7;
            u16x8 v;
            #pragma unroll
            for (int e = 0; e < 8; ++e) v[e] = smu.tle[kc * 8 + e][nn];
            *(u16x8*)(WoT + (size_t)(n0 + nn) * H + k0 + kc * 8) = v;
        }
    }
}

// ---- D3: recurrence — 32 independent blocks (1/batch row), i8 dot4 ----------
__global__ __launch_bounds__(1024) void lstm_recur_i8(
        const unsigned short* __restrict__ xwq, const uint4* __restrict__ UQ8,
        const float* __restrict__ sc, unsigned short* __restrict__ hb) {
    __shared__ unsigned int hq8[2][64];     // int8 h, ping-pong, 4 k per dword
    __shared__ int4 red[4][256];            // per-quarter gate sums
    const int b = blockIdx.x, tid = threadIdx.x;
    const int j = tid & 255, q = tid >> 8;
    const float f0 = sc[0] * (1.f / 16129.f), f1 = sc[1] * (1.f / 16129.f);
    const float f2 = sc[2] * (1.f / 16129.f), f3 = sc[3] * (1.f / 16129.f);
    float c_ = 0.f;

    for (int t = 0; t < T; ++t) {
        if (t > 0) {
            const uint4* up = UQ8 + (size_t)(q * 16) * 256 + j;
            const unsigned int* hrow = hq8[t & 1] + q * 16;
            int a0 = 0, a1 = 0, a2 = 0, a3 = 0;
            #pragma unroll
            for (int m = 0; m < 16; ++m) {
                uint4 u = up[(size_t)m * 256];
                unsigned int hv = hrow[m];
                a0 = dot4i8(u.x, hv, a0);
                a1 = dot4i8(u.y, hv, a1);
                a2 = dot4i8(u.z, hv, a2);
                a3 = dot4i8(u.w, hv, a3);
            }
            red[q][j] = make_int4(a0, a1, a2, a3);
        }
        __syncthreads();
        if (tid < 256) {
            ushort4 xw = *(const ushort4*)(xwq + ((size_t)(t * 32 + b) * 256 + j) * 4);
            float pi = bf2f(xw.x), pf = bf2f(xw.y), po = bf2f(xw.z), pc = bf2f(xw.w);
            if (t > 0) {
                int4 r0 = red[0][j], r1 = red[1][j], r2 = red[2][j], r3 = red[3][j];
                pi += (float)(r0.x + r1.x + r2.x + r3.x) * f0;
                pf += (float)(r0.y + r1.y + r2.y + r3.y) * f1;
                po += (float)(r0.z + r1.z + r2.z + r3.z) * f2;
                pc += (float)(r0.w + r1.w + r2.w + r3.w) * f3;
            }
            c_ = sigmoidf_(pf) * c_ + sigmoidf_(pi) * tanhf_(pc);
            float h = sigmoidf_(po) * tanhf_(c_);
            hb[(size_t)(t * B + b) * H + j] = f2bf(h);
            ((char*)hq8[(t + 1) & 1])[j] = (char)__float2int_rn(h * 127.f);
        }
        __syncthreads();
    }
}

// ---- D4: logits GEMM — r15 config (fastest measured: 171us): NC=128,
// (512,4): VGPR capped at 64 -> 2 blocks/CU / 4 waves/SIMD (43% occ). The
// cap spills ~2 Bf frags to scratch (L1-resident) — measured cheaper than
// the no-spill alternatives (r16: 72 VGPR -> 22% occ -> 206us; r17: NC=64
// no-spill -> doubles A traffic -> 232us). grid (250 vchunks, 2 row-halves);
// 64-row dbuf A tiles, prefetch-ahead global_load_lds; B in 64 VGPR Bf;
// max-free fused softmax. tgt_l race-free: written for rb+1 between the two
// trailing barriers (prologue writes rb=0 before the first barrier).
// LDS: linear dest + pre-swizzled source + swizzled read (verified r13-r17).
__global__ __launch_bounds__(512, 4) void lstm_logits_mfma(
        const unsigned short* __restrict__ hb, const unsigned short* __restrict__ WoT,
        const float* __restrict__ bo, const int* __restrict__ tgtrow,
        float* __restrict__ ps, float* __restrict__ tl) {
    __shared__ char ab0[32768];          // 64-row tile buffer 0
    __shared__ char ab1[32768];          // 64-row tile buffer 1
    __shared__ float s_red[4][72];       // per-colwave row sums (pad)
    __shared__ int   tgt_l[64];
    const int tid = threadIdx.x, lane = tid & 63, wid = tid >> 6;   // 8 waves
    const int wr = wid >> 2, wc = wid & 3;          // 2 row-32s x 4 col-32s
    const int lr = lane & 15, lg = lane >> 4;
    const int swz = lr & 7;
    const int vb = blockIdx.x * NC;
    const int rbase = blockIdx.y * (NROW / 2);      // this block's 2048 rows

    // stage one 32KB 64-row tile: 8 waves x 4 instr x (64 lanes x 16B)
    #define STAGE32(dst_, srcbase_) { _Pragma("unroll") \
        for (int i_ = 0; i_ < 4; ++i_) { \
            int chunk_ = (wid * 4 + i_) * 64 + lane; \
            int row_ = chunk_ >> 5, c16_ = chunk_ & 31; \
            int srcc_ = c16_ ^ (row_ & 7); \
            stage16((const char*)(srcbase_) + row_ * 512 + srcc_ * 16, \
                    (dst_) + (wid * 4 + i_) * 1024, lane); \
        } }

    // ---- prologue: B slice (128 rows) in two halves -> registers ----
    STAGE32(ab0, (const char*)(WoT + (size_t)vb * H));              // B rows 0-63
    STAGE32(ab1, (const char*)(WoT + (size_t)(vb + 64) * H));       // B rows 64-127
    if (tid < 64) tgt_l[tid] = tgtrow[rbase + tid];   // targets for rb=0
    __syncthreads();                                  // drains vmcnt+lgkmcnt
    bf16x8 Bf[2][8];
    {
        const char* bBase = (wc < 2) ? (ab0 + (wc * 32 + lr) * 512)
                                     : (ab1 + ((wc - 2) * 32 + lr) * 512);
        #pragma unroll
        for (int nf = 0; nf < 2; ++nf)
            #pragma unroll
            for (int ks = 0; ks < 8; ++ks)
                Bf[nf][ks] = *(const bf16x8*)(bBase + nf * 16 * 512 + (((ks * 4 + lg) ^ swz) << 4));
    }
    float bocol[2] = { bo[vb + wc * 32 + lr], bo[vb + wc * 32 + 16 + lr] };
    __syncthreads();                                  // Bf reads drained everywhere
    STAGE32(ab0, (const char*)(hb + (size_t)rbase * H));            // A tile 0
    __syncthreads();                                  // A0 landed

    for (int rb = 0; rb < 32; ++rb) {                 // 32 x 64-row tiles
        char* curb = (rb & 1) ? ab1 : ab0;
        char* nxtb = (rb & 1) ? ab0 : ab1;
        if (rb + 1 < 32)                              // prefetch A[rb+1] (async)
            STAGE32(nxtb, (const char*)(hb + (size_t)(rbase + (rb + 1) * 64) * H));

        f32x4 acc[2][2] = {};
        const char* aBase = curb + (wr * 32 + lr) * 512;
        #pragma unroll
        for (int ks = 0; ks < 8; ++ks) {
            const int co = ((ks * 4 + lg) ^ swz) << 4;
            bf16x8 a0 = *(const bf16x8*)(aBase + co);
            bf16x8 a1 = *(const bf16x8*)(aBase + 16 * 512 + co);
            acc[0][0] = __builtin_amdgcn_mfma_f32_16x16x32_bf16(a0, Bf[0][ks], acc[0][0], 0, 0, 0);
            acc[0][1] = __builtin_amdgcn_mfma_f32_16x16x32_bf16(a0, Bf[1][ks], acc[0][1], 0, 0, 0);
            acc[1][0] = __builtin_amdgcn_mfma_f32_16x16x32_bf16(a1, Bf[0][ks], acc[1][0], 0, 0, 0);
            acc[1][1] = __builtin_amdgcn_mfma_f32_16x16x32_bf16(a1, Bf[1][ks], acc[1][1], 0, 0, 0);
        }

        // ---- fused softmax partials, in-register ----
        const int col0 = vb + wc * 32 + lr, col1 = col0 + 16;
        #pragma unroll
        for (int mf = 0; mf < 2; ++mf)
            #pragma unroll
            for (int r = 0; r < 4; ++r) {
                const int row_l = wr * 32 + mf * 16 + lg * 4 + r;
                float v0 = acc[mf][0][r] + bocol[0];
                float v1 = acc[mf][1][r] + bocol[1];
                const int tg = tgt_l[row_l];
                if (tg == col0) tl[rbase + rb * 64 + row_l] = v0;
                if (tg == col1) tl[rbase + rb * 64 + row_l] = v1;
                float e = __expf(v0) + __expf(v1);
                e += __shfl_xor(e, 1); e += __shfl_xor(e, 2);
                e += __shfl_xor(e, 4); e += __shfl_xor(e, 8);
                if (lr == 0) s_red[wc][row_l] = e;
            }
        __syncthreads();                              // s_red ready (also drains prefetch)
        if (tid < 64) {
            ps[(size_t)blockIdx.x * NROW + rbase + rb * 64 + tid] =
                s_red[0][tid] + s_red[1][tid] + s_red[2][tid] + s_red[3][tid];
            if (rb + 1 < 32)                          // targets for rb+1 (published below)
                tgt_l[tid] = tgtrow[rbase + (rb + 1) * 64 + tid];
        }
        __syncthreads();                              // s_red consumed + tgt_l/A[rb+1] published
    }
    #undef STAGE32
}

// ---- D5: combine chunk sums, reduce NLL — 64 blocks, 4 c-quarters/row --------
__global__ __launch_bounds__(256) void lstm_lse(
        const float* __restrict__ ps, const float* __restrict__ tl,
        float* __restrict__ out) {
    __shared__ float sp[4][80];
    const int tid = threadIdx.x;
    const int rl = tid & 63, cq = tid >> 6;
    const int row = blockIdx.x * 64 + rl;
    float s = 0.f;
    #pragma unroll 4
    for (int c = cq; c < NVB; c += 4)
        s += ps[(size_t)c * NROW + row];
    sp[cq][rl] = s;
    __syncthreads();
    if (tid < 64) {
        float nll = logf(sp[0][rl] + sp[1][rl] + sp[2][rl] + sp[3][rl]) - tl[row];
        #pragma unroll
        for (int off = 32; off > 0; off >>= 1) nll += __shfl_xor(nll, off);
        if (rl == 0) atomicAdd(out, nll);
    }
}

extern "C" void kernel_launch(void* const* d_in, const int* in_sizes, int n_in,
                              void* d_out, int out_size, void* d_ws, size_t ws_size,
                              hipStream_t stream) {
    const int*   x     = (const int*)d_in[0];
    const float* emb   = (const float*)d_in[1];
    const float* Wi    = (const float*)d_in[2];
    const float* Ui    = (const float*)d_in[3];
    const float* bi    = (const float*)d_in[4];
    const float* Wf    = (const float*)d_in[5];
    const float* Uf    = (const float*)d_in[6];
    const float* bf    = (const float*)d_in[7];
    const float* Wog   = (const float*)d_in[8];
    const float* Uog   = (const float*)d_in[9];
    const float* bog   = (const float*)d_in[10];
    const float* Wc    = (const float*)d_in[11];
    const float* Uc    = (const float*)d_in[12];
    const float* bc    = (const float*)d_in[13];
    const float* Wo    = (const float*)d_in[14];
    const float* bo    = (const float*)d_in[15];
    const int*   start = (const int*)d_in[16];
    float* ws  = (float*)d_ws;
    float* out = (float*)d_out;

    float*          xs   = ws + OFF_XS;
    unsigned short* xwq  = (unsigned short*)(ws + OFF_XW);
    unsigned short* WoT  = (unsigned short*)(ws + OFF_XW);   // aliases xwq (dead after recur)
    unsigned short* hbf  = (unsigned short*)(ws + OFF_HB);
    float*          psB  = ws + OFF_PS;
    float*          tlB  = ws + OFF_TL;
    unsigned int*   UQ8  = (unsigned int*)(ws + OFF_U8);
    float*          scB  = ws + OFF_SC;
    int*            tgtr = (int*)(ws + OFF_TGT);

    // D1: embed (1024 blocks) || umax (4 blocks)
    lstm_embed_umax<<<1028, 256, 0, stream>>>(x, emb, start, xs, out, tgtr,
                                              Ui, Uf, Uog, Uc, scB);
    // D2: xw (128) || uq8 (64) || wot (2000)
    lstm_xw_uq8_wot<<<T + 64 + 2000, 256, 0, stream>>>(
        xs, xwq, Wi, Wf, Wog, Wc, bi, bf, bog, bc,
        Ui, Uf, Uog, Uc, scB, UQ8, Wo, WoT);
    // D3: recurrence
    lstm_recur_i8<<<B, 1024, 0, stream>>>(xwq, (const uint4*)UQ8, scB, hbf);
    // D4: logits + fused softmax partials
    lstm_logits_mfma<<<dim3(NVB, 2), 512, 0, stream>>>(hbf, WoT, bo, tgtr, psB, tlB);
    // D5: combine + NLL
    lstm_lse<<<NROW / 64, 256, 0, stream>>>(psB, tlB, out);
}